// Round 3
// baseline (479.839 us; speedup 1.0000x reference)
//
#include <hip/hip_runtime.h>

#define N 256
#define BLK 1024
#define RPT 8   // rows per thread (contiguous)
#define CPT 8   // cols per thread (stride 32: col = cg + 32k)
#define NWAVE 16
#define N_ITERS 21

__device__ __forceinline__ float wred_max32(float v) {
  v = fmaxf(v, __shfl_xor(v, 16));
  v = fmaxf(v, __shfl_xor(v, 8));
  v = fmaxf(v, __shfl_xor(v, 4));
  v = fmaxf(v, __shfl_xor(v, 2));
  v = fmaxf(v, __shfl_xor(v, 1));
  return v;
}
__device__ __forceinline__ float wred_sum32(float v) {
  v += __shfl_xor(v, 16);
  v += __shfl_xor(v, 8);
  v += __shfl_xor(v, 4);
  v += __shfl_xor(v, 2);
  v += __shfl_xor(v, 1);
  return v;
}

// One block = one 256x256 matrix, 16 waves, exactly one block per CU
// (amdgpu_waves_per_eu(4,4) => 128-VGPR budget so b[8][8] stays resident).
// Thread (rg = tid>>5, cg = tid&31) owns rows rg*8..+7, cols cg+32k.
// Sinkhorn in dual-potential form: la = b - U_i - V_j, b static in registers.
// All math in log2 domain: b = x * log2(e)/T.
__global__ __launch_bounds__(BLK)
__attribute__((amdgpu_waves_per_eu(4, 4)))
void sinkhorn_kernel(const float* __restrict__ x, float* __restrict__ out) {
  __shared__ float lds_m[NWAVE * N];  // per-wave partial col max
  __shared__ float lds_s[NWAVE * N];  // per-wave partial col sum
  __shared__ float lds_V[N];

  const int tid = threadIdx.x;
  const int cg = tid & 31;
  const int rg = tid >> 5;
  const int wv = tid >> 6;  // wave index 0..15
  const int r0 = rg * RPT;
  const long mat = blockIdx.x;
  const float SCALE = 144.2695040888963407f;  // log2(e)/0.01

  const float* __restrict__ src = x + mat * (long)(N * N);
  float b[RPT][CPT];
  #pragma unroll
  for (int r = 0; r < RPT; ++r) {
    #pragma unroll
    for (int c = 0; c < CPT; ++c)
      b[r][c] = src[(r0 + r) * N + cg + c * 32] * SCALE;
  }

  float U[RPT], V[CPT];
  #pragma unroll
  for (int c = 0; c < CPT; ++c) V[c] = 0.f;

  for (int it = 0; it < N_ITERS; ++it) {
    // ---- row step: U_i = lse2_j(b_ij - V_j); butterfly over the 32 lanes
    // of this row group.
    #pragma unroll
    for (int r = 0; r < RPT; ++r) {
      float m = -3.0e38f;
      #pragma unroll
      for (int c = 0; c < CPT; ++c) m = fmaxf(m, b[r][c] - V[c]);
      m = wred_max32(m);
      float s = 0.f;
      #pragma unroll
      for (int c = 0; c < CPT; ++c)
        s += __builtin_amdgcn_exp2f(b[r][c] - V[c] - m);
      s = wred_sum32(s);
      U[r] = m + __builtin_amdgcn_logf(s);  // v_log_f32 = log2
    }

    // ---- col step: V_j = lse2_i(b_ij - U_i), online (max,sum) pairs.
    float lm[CPT], ls[CPT];
    #pragma unroll
    for (int c = 0; c < CPT; ++c) lm[c] = -3.0e38f;
    #pragma unroll
    for (int r = 0; r < RPT; ++r) {
      float u = U[r];
      #pragma unroll
      for (int c = 0; c < CPT; ++c) lm[c] = fmaxf(lm[c], b[r][c] - u);
    }
    #pragma unroll
    for (int c = 0; c < CPT; ++c) {
      float s = 0.f;
      #pragma unroll
      for (int r = 0; r < RPT; ++r)
        s += __builtin_amdgcn_exp2f(b[r][c] - U[r] - lm[c]);
      ls[c] = s;
    }
    // merge the two row-groups sharing this wave (lane ^ 32, same cols)
    #pragma unroll
    for (int c = 0; c < CPT; ++c) {
      float om = __shfl_xor(lm[c], 32);
      float os = __shfl_xor(ls[c], 32);
      float M2 = fmaxf(lm[c], om);
      ls[c] = ls[c] * __builtin_amdgcn_exp2f(lm[c] - M2) +
              os * __builtin_amdgcn_exp2f(om - M2);
      lm[c] = M2;
    }
    if ((tid & 63) < 32) {
      #pragma unroll
      for (int c = 0; c < CPT; ++c) {
        lds_m[wv * N + cg + c * 32] = lm[c];  // lane-distinct banks
        lds_s[wv * N + cg + c * 32] = ls[c];
      }
    }
    __syncthreads();
    if (tid < N) {
      float M = lds_m[tid];
      #pragma unroll
      for (int p = 1; p < NWAVE; ++p) M = fmaxf(M, lds_m[p * N + tid]);
      float S = 0.f;
      #pragma unroll
      for (int p = 0; p < NWAVE; ++p)
        S += lds_s[p * N + tid] *
             __builtin_amdgcn_exp2f(lds_m[p * N + tid] - M);
      lds_V[tid] = M + __builtin_amdgcn_logf(S);
    }
    __syncthreads();
    #pragma unroll
    for (int c = 0; c < CPT; ++c) V[c] = lds_V[cg + c * 32];
  }

  // ---- output: P = 2^(b - U_i - V_j), coalesced stores
  float* __restrict__ dst = out + mat * (long)(N * N);
  #pragma unroll
  for (int r = 0; r < RPT; ++r) {
    float u = U[r];
    #pragma unroll
    for (int c = 0; c < CPT; ++c)
      dst[(r0 + r) * N + cg + c * 32] =
          __builtin_amdgcn_exp2f(b[r][c] - u - V[c]);
  }
}

extern "C" void kernel_launch(void* const* d_in, const int* in_sizes, int n_in,
                              void* d_out, int out_size, void* d_ws, size_t ws_size,
                              hipStream_t stream) {
  const float* x = (const float*)d_in[0];
  float* out = (float*)d_out;
  int B = in_sizes[0] / (N * N);
  hipLaunchKernelGGL(sinkhorn_kernel, dim3(B), dim3(BLK), 0, stream, x, out);
}

// Round 4
// 179.517 us; speedup vs baseline: 2.6729x; 2.6729x over previous
//
#include <hip/hip_runtime.h>

#define N 256
#define BLK 1024
#define RPT 8   // rows per thread (contiguous)
#define CPT 8   // cols per thread (stride 32: col = cg + 32k)
#define NWAVE 16
#define N_ITERS 21

__device__ __forceinline__ float wred_max32(float v) {
  v = fmaxf(v, __shfl_xor(v, 16));
  v = fmaxf(v, __shfl_xor(v, 8));
  v = fmaxf(v, __shfl_xor(v, 4));
  v = fmaxf(v, __shfl_xor(v, 2));
  v = fmaxf(v, __shfl_xor(v, 1));
  return v;
}
__device__ __forceinline__ float wred_sum32(float v) {
  v += __shfl_xor(v, 16);
  v += __shfl_xor(v, 8);
  v += __shfl_xor(v, 4);
  v += __shfl_xor(v, 2);
  v += __shfl_xor(v, 1);
  return v;
}

// One block = one 256x256 matrix, 16 waves.
// Thread (rg = tid>>5, cg = tid&31) owns rows rg*8..+7, cols cg+32k.
// Iteration 0: log2-domain, fully max-stabilized (rescues degenerate cols).
// Iterations 1..20: pure probability domain. Safe because after one full
// (row,col) normalization all row/col sums stay in [2^-16, 256] (bounded
// induction on lse), so rcp never sees 0 and nothing overflows.
__global__ __launch_bounds__(BLK, 4)
void sinkhorn_kernel(const float* __restrict__ x, float* __restrict__ out) {
  __shared__ float lds_a[NWAVE * N];  // per-wave partials (max or sum)
  __shared__ float lds_b[N];          // reduced per-col value (max or rcp)

  const int tid = threadIdx.x;
  const int cg = tid & 31;
  const int wv = tid >> 6;            // wave index 0..15
  const int r0 = (tid >> 5) * RPT;
  const long mat = blockIdx.x;
  const float SCALE = 144.2695040888963407f;  // log2(e)/0.01

  const float* __restrict__ src = x + mat * (long)(N * N);
  float p[RPT][CPT];  // starts as t = x*SCALE (log2); becomes probability
  #pragma unroll
  for (int r = 0; r < RPT; ++r) {
    #pragma unroll
    for (int c = 0; c < CPT; ++c)
      p[r][c] = src[(r0 + r) * N + cg + c * 32] * SCALE;
  }

  // ============ iteration 0: log2 domain, stabilized ============
  // row: t -= lse2_row(t)
  #pragma unroll
  for (int r = 0; r < RPT; ++r) {
    float m = p[r][0];
    #pragma unroll
    for (int c = 1; c < CPT; ++c) m = fmaxf(m, p[r][c]);
    m = wred_max32(m);
    float s = 0.f;
    #pragma unroll
    for (int c = 0; c < CPT; ++c) s += __builtin_amdgcn_exp2f(p[r][c] - m);
    s = wred_sum32(s);
    float L = m + __builtin_amdgcn_logf(s);  // v_log_f32 = log2
    #pragma unroll
    for (int c = 0; c < CPT; ++c) p[r][c] -= L;
  }
  // col: stabilized lse -> leave p in probability domain (col-normalized)
  {
    float lm[CPT];
    #pragma unroll
    for (int c = 0; c < CPT; ++c) {
      float v = p[0][c];
      #pragma unroll
      for (int r = 1; r < RPT; ++r) v = fmaxf(v, p[r][c]);
      lm[c] = fmaxf(v, __shfl_xor(v, 32));
    }
    if ((tid & 63) < 32) {
      #pragma unroll
      for (int c = 0; c < CPT; ++c) lds_a[wv * N + cg + c * 32] = lm[c];
    }
    __syncthreads();
    if (tid < N) {
      float M = lds_a[tid];
      #pragma unroll
      for (int q = 1; q < NWAVE; ++q) M = fmaxf(M, lds_a[q * N + tid]);
      lds_b[tid] = M;
    }
    __syncthreads();
    #pragma unroll
    for (int c = 0; c < CPT; ++c) lm[c] = lds_b[cg + c * 32];

    float ps[CPT];
    #pragma unroll
    for (int c = 0; c < CPT; ++c) ps[c] = 0.f;
    #pragma unroll
    for (int r = 0; r < RPT; ++r) {
      #pragma unroll
      for (int c = 0; c < CPT; ++c) {
        float f = __builtin_amdgcn_exp2f(p[r][c] - lm[c]);
        p[r][c] = f;
        ps[c] += f;
      }
    }
    #pragma unroll
    for (int c = 0; c < CPT; ++c) ps[c] += __shfl_xor(ps[c], 32);
    if ((tid & 63) < 32) {
      #pragma unroll
      for (int c = 0; c < CPT; ++c) lds_a[wv * N + cg + c * 32] = ps[c];
    }
    __syncthreads();
    if (tid < N) {
      float S = 0.f;
      #pragma unroll
      for (int q = 0; q < NWAVE; ++q) S += lds_a[q * N + tid];
      lds_b[tid] = __builtin_amdgcn_rcpf(S);
    }
    __syncthreads();
    #pragma unroll
    for (int c = 0; c < CPT; ++c) {
      float h = lds_b[cg + c * 32];
      #pragma unroll
      for (int r = 0; r < RPT; ++r) p[r][c] *= h;
    }
  }

  // ============ iterations 1..20: probability domain ============
  for (int it = 1; it < N_ITERS; ++it) {
    float ps[CPT];
    #pragma unroll
    for (int c = 0; c < CPT; ++c) ps[c] = 0.f;
    #pragma unroll
    for (int r = 0; r < RPT; ++r) {
      float s = 0.f;
      #pragma unroll
      for (int c = 0; c < CPT; ++c) s += p[r][c];
      s = wred_sum32(s);
      float g = __builtin_amdgcn_rcpf(s);
      #pragma unroll
      for (int c = 0; c < CPT; ++c) {
        p[r][c] *= g;          // row normalize
        ps[c] += p[r][c];      // col partial on normalized values
      }
    }
    #pragma unroll
    for (int c = 0; c < CPT; ++c) ps[c] += __shfl_xor(ps[c], 32);
    if ((tid & 63) < 32) {
      #pragma unroll
      for (int c = 0; c < CPT; ++c) lds_a[wv * N + cg + c * 32] = ps[c];
    }
    __syncthreads();
    if (tid < N) {
      float S = 0.f;
      #pragma unroll
      for (int q = 0; q < NWAVE; ++q) S += lds_a[q * N + tid];
      lds_b[tid] = __builtin_amdgcn_rcpf(S);
    }
    __syncthreads();
    #pragma unroll
    for (int c = 0; c < CPT; ++c) {
      float h = lds_b[cg + c * 32];
      #pragma unroll
      for (int r = 0; r < RPT; ++r) p[r][c] *= h;  // col normalize
    }
  }

  // ============ output: p already = exp(log_alpha) ============
  float* __restrict__ dst = out + mat * (long)(N * N);
  #pragma unroll
  for (int r = 0; r < RPT; ++r) {
    #pragma unroll
    for (int c = 0; c < CPT; ++c)
      dst[(r0 + r) * N + cg + c * 32] = p[r][c];
  }
}

extern "C" void kernel_launch(void* const* d_in, const int* in_sizes, int n_in,
                              void* d_out, int out_size, void* d_ws, size_t ws_size,
                              hipStream_t stream) {
  const float* x = (const float*)d_in[0];
  float* out = (float*)d_out;
  int B = in_sizes[0] / (N * N);
  hipLaunchKernelGGL(sinkhorn_kernel, dim3(B), dim3(BLK), 0, stream, x, out);
}

// Round 5
// 135.771 us; speedup vs baseline: 3.5342x; 1.3222x over previous
//
#include <hip/hip_runtime.h>

typedef __attribute__((ext_vector_type(2))) float f32x2;

#define N 256
#define BLK 1024
#define N_ITERS 21

// ---- DPP helpers (all lanes active at every call site) ----
template <int CTRL>
__device__ __forceinline__ float dppmov(float v) {
  return __int_as_float(__builtin_amdgcn_update_dpp(
      0, __float_as_int(v), CTRL, 0xF, 0xF, true));
}
__device__ __forceinline__ float swz_xor16(float v) {
  return __int_as_float(
      __builtin_amdgcn_ds_swizzle(__float_as_int(v), 0x401F));  // xor 16
}
// 32-lane reductions (independently within each half-wave):
// row_ror 1,2,4,8 within 16 lanes (VALU-only DPP), then one xor16 swizzle.
__device__ __forceinline__ float rsum32(float v) {
  v += dppmov<0x121>(v);
  v += dppmov<0x122>(v);
  v += dppmov<0x124>(v);
  v += dppmov<0x128>(v);
  v += swz_xor16(v);
  return v;
}
__device__ __forceinline__ float rmax32(float v) {
  v = fmaxf(v, dppmov<0x121>(v));
  v = fmaxf(v, dppmov<0x122>(v));
  v = fmaxf(v, dppmov<0x124>(v));
  v = fmaxf(v, dppmov<0x128>(v));
  v = fmaxf(v, swz_xor16(v));
  return v;
}
__device__ __forceinline__ f32x2 pkmax(f32x2 a, f32x2 b) {
  f32x2 r;
  r.x = fmaxf(a.x, b.x);
  r.y = fmaxf(a.y, b.y);
  return r;
}

// One block = one 256x256 matrix, 16 waves.
// Thread (rg = tid>>5, cg = tid&31) owns rows rg*8..+7, cols cg*8..cg*8+7
// (contiguous -> float4 global I/O). p held as f32x2[8][4] (packed math).
// Iteration 0 in stabilized log2 domain (rescues degenerate cols); the other
// 20 iterations in probability domain with the col factor V applied lazily
// at the START of the next sweep (single fused sweep per iteration).
// Col reduce: partials in LDS [32 row-groups][256 cols], bank-swizzled;
// all 1024 threads reduce (8 loads + 2 quad-perm DPP combines).
__global__ __launch_bounds__(BLK, 2)
void sinkhorn_kernel(const float* __restrict__ x, float* __restrict__ out) {
  __shared__ float lds_part[32 * N];  // [rg][k*32 + ((cg+rg)&31)]
  __shared__ float lds_v[N];          // transposed: col c at (c&7)*32 + (c>>3)

  const int tid = threadIdx.x;
  const int cg = tid & 31;
  const int rg = tid >> 5;  // 0..31 = partial-row id
  const int r0 = rg * 8;
  const long mat = blockIdx.x;
  const float SCALE = 144.2695040888963407f;  // log2(e)/0.01

  // reduce-phase identity: thread handles col c = (cr&31)*8 + (cr>>5)
  const int cr = tid >> 2;  // 0..255
  const int q = tid & 3;
  const int cg_r = cr & 31;
  const int k_r = cr >> 5;
  const int red_base = k_r * 32;        // + h*N + ((cg_r+h)&31)
  const int vslot = k_r * 32 + cg_r;    // lds_v slot for col c

  // ---- load + scale (float4, fully coalesced) ----
  const float4* __restrict__ src4 =
      reinterpret_cast<const float4*>(x + mat * (long)(N * N));
  f32x2 p[8][4];
  #pragma unroll
  for (int r = 0; r < 8; ++r) {
    float4 a = src4[(r0 + r) * 64 + cg * 2];
    float4 b = src4[(r0 + r) * 64 + cg * 2 + 1];
    f32x2 t;
    t.x = a.x; t.y = a.y; p[r][0] = t * SCALE;
    t.x = a.z; t.y = a.w; p[r][1] = t * SCALE;
    t.x = b.x; t.y = b.y; p[r][2] = t * SCALE;
    t.x = b.z; t.y = b.w; p[r][3] = t * SCALE;
  }

  f32x2 Vr[4];  // pending col factor (applied lazily)

  // ================= iteration 0: log2 domain, stabilized =================
  #pragma unroll
  for (int r = 0; r < 8; ++r) {
    f32x2 m2 = pkmax(pkmax(p[r][0], p[r][1]), pkmax(p[r][2], p[r][3]));
    float m = rmax32(fmaxf(m2.x, m2.y));
    float s = 0.f;
    #pragma unroll
    for (int j = 0; j < 4; ++j) {
      s += __builtin_amdgcn_exp2f(p[r][j].x - m);
      s += __builtin_amdgcn_exp2f(p[r][j].y - m);
    }
    s = rsum32(s);
    float L = m + __builtin_amdgcn_logf(s);  // v_log_f32 = log2
    #pragma unroll
    for (int j = 0; j < 4; ++j) p[r][j] -= L;
  }
  {
    // col max partials
    f32x2 cm[4];
    #pragma unroll
    for (int j = 0; j < 4; ++j) cm[j] = p[0][j];
    #pragma unroll
    for (int r = 1; r < 8; ++r)
      #pragma unroll
      for (int j = 0; j < 4; ++j) cm[j] = pkmax(cm[j], p[r][j]);
    const int wslot = (cg + rg) & 31;
    #pragma unroll
    for (int j = 0; j < 4; ++j) {
      lds_part[rg * N + (2 * j) * 32 + wslot] = cm[j].x;
      lds_part[rg * N + (2 * j + 1) * 32 + wslot] = cm[j].y;
    }
    __syncthreads();
    float M = -3.0e38f;
    #pragma unroll
    for (int jj = 0; jj < 8; ++jj) {
      int h = q * 8 + jj;
      M = fmaxf(M, lds_part[h * N + red_base + ((cg_r + h) & 31)]);
    }
    M = fmaxf(M, dppmov<0xB1>(M));  // quad xor1
    M = fmaxf(M, dppmov<0x4E>(M));  // quad xor2
    if (q == 0) lds_v[vslot] = M;
    __syncthreads();
    // exp + col-sum partials
    f32x2 Mk[4];
    #pragma unroll
    for (int j = 0; j < 4; ++j) {
      Mk[j].x = lds_v[(2 * j) * 32 + cg];
      Mk[j].y = lds_v[(2 * j + 1) * 32 + cg];
    }
    f32x2 ps[4];
    #pragma unroll
    for (int j = 0; j < 4; ++j) { ps[j].x = 0.f; ps[j].y = 0.f; }
    #pragma unroll
    for (int r = 0; r < 8; ++r) {
      #pragma unroll
      for (int j = 0; j < 4; ++j) {
        f32x2 v;
        v.x = __builtin_amdgcn_exp2f(p[r][j].x - Mk[j].x);
        v.y = __builtin_amdgcn_exp2f(p[r][j].y - Mk[j].y);
        p[r][j] = v;
        ps[j] += v;
      }
    }
    #pragma unroll
    for (int j = 0; j < 4; ++j) {
      lds_part[rg * N + (2 * j) * 32 + wslot] = ps[j].x;
      lds_part[rg * N + (2 * j + 1) * 32 + wslot] = ps[j].y;
    }
    __syncthreads();
    float S = 0.f;
    #pragma unroll
    for (int jj = 0; jj < 8; ++jj) {
      int h = q * 8 + jj;
      S += lds_part[h * N + red_base + ((cg_r + h) & 31)];
    }
    S += dppmov<0xB1>(S);
    S += dppmov<0x4E>(S);
    if (q == 0) lds_v[vslot] = __builtin_amdgcn_rcpf(S);
    __syncthreads();
    #pragma unroll
    for (int j = 0; j < 4; ++j) {
      Vr[j].x = lds_v[(2 * j) * 32 + cg];
      Vr[j].y = lds_v[(2 * j + 1) * 32 + cg];
    }
  }

  // ====== iterations 1..20: probability domain, one fused sweep each ======
  for (int it = 1; it < N_ITERS; ++it) {
    f32x2 ps[4];
    #pragma unroll
    for (int j = 0; j < 4; ++j) { ps[j].x = 0.f; ps[j].y = 0.f; }
    #pragma unroll
    for (int r = 0; r < 8; ++r) {
      // lazy col-normalize of previous iteration
      p[r][0] *= Vr[0]; p[r][1] *= Vr[1];
      p[r][2] *= Vr[2]; p[r][3] *= Vr[3];
      f32x2 t = (p[r][0] + p[r][1]) + (p[r][2] + p[r][3]);
      float g = __builtin_amdgcn_rcpf(rsum32(t.x + t.y));
      p[r][0] *= g; p[r][1] *= g; p[r][2] *= g; p[r][3] *= g;
      ps[0] += p[r][0]; ps[1] += p[r][1];
      ps[2] += p[r][2]; ps[3] += p[r][3];
    }
    const int wslot = (cg + rg) & 31;
    #pragma unroll
    for (int j = 0; j < 4; ++j) {
      lds_part[rg * N + (2 * j) * 32 + wslot] = ps[j].x;
      lds_part[rg * N + (2 * j + 1) * 32 + wslot] = ps[j].y;
    }
    __syncthreads();
    float S = 0.f;
    #pragma unroll
    for (int jj = 0; jj < 8; ++jj) {
      int h = q * 8 + jj;
      S += lds_part[h * N + red_base + ((cg_r + h) & 31)];
    }
    S += dppmov<0xB1>(S);
    S += dppmov<0x4E>(S);
    if (q == 0) lds_v[vslot] = __builtin_amdgcn_rcpf(S);
    __syncthreads();
    #pragma unroll
    for (int j = 0; j < 4; ++j) {
      Vr[j].x = lds_v[(2 * j) * 32 + cg];
      Vr[j].y = lds_v[(2 * j + 1) * 32 + cg];
    }
  }

  // ---- final lazy col-normalize + store (float4) ----
  float4* __restrict__ dst4 =
      reinterpret_cast<float4*>(out + mat * (long)(N * N));
  #pragma unroll
  for (int r = 0; r < 8; ++r) {
    f32x2 a = p[r][0] * Vr[0];
    f32x2 b = p[r][1] * Vr[1];
    f32x2 c = p[r][2] * Vr[2];
    f32x2 d = p[r][3] * Vr[3];
    dst4[(r0 + r) * 64 + cg * 2] = make_float4(a.x, a.y, b.x, b.y);
    dst4[(r0 + r) * 64 + cg * 2 + 1] = make_float4(c.x, c.y, d.x, d.y);
  }
}

extern "C" void kernel_launch(void* const* d_in, const int* in_sizes, int n_in,
                              void* d_out, int out_size, void* d_ws, size_t ws_size,
                              hipStream_t stream) {
  const float* x = (const float*)d_in[0];
  float* out = (float*)d_out;
  int B = in_sizes[0] / (N * N);
  hipLaunchKernelGGL(sinkhorn_kernel, dim3(B), dim3(BLK), 0, stream, x, out);
}